// Round 2
// baseline (336.788 us; speedup 1.0000x reference)
//
#include <hip/hip_runtime.h>
#include <math.h>
#include <stdint.h>

// ---------------------------------------------------------------------------
// Mlp_8744553415182 on MI355X (gfx950). I/O is FP32; compute in bf16 MFMA.
// Pipeline:
//   0. memset counts[4096] = 0
//   1. f2b_kernel x->xb, W1->w1b (both parked in d_out), W2->w2b (ws)
//   2. pad_kernel:    xpad[8192,128], w1pad[4096,128] bf16 (cols>=103 -> 0)
//   3. scales_kernel: s_x[8192], s_w[4096], s_b from FP32 originals
//   4. topk_gemm:     counts[n] += #(x_topk . w1_topk + b1 > 0)  (MFMA K=128)
//   5. gemm1_gelu:    h = gelu(x . W1^T + b1) bf16, ALL channels (MFMA K=1024)
//   6. fixup_kernel:  channels with counts<=2048 -> quantized path (FP32 exact;
//                     statistically zero channels fire -> near-free)
//   7. gemm2_bias:    out = h . W2^T + b2, FP32 out               (MFMA K=4096)
// ---------------------------------------------------------------------------

typedef __bf16 v8bf __attribute__((ext_vector_type(8)));
typedef float v4f __attribute__((ext_vector_type(4)));

#define AS_G __attribute__((address_space(1)))
#define AS_L __attribute__((address_space(3)))

__device__ __forceinline__ unsigned short f2bf(float f) {
    union { float f; unsigned int i; } v; v.f = f;
    unsigned int r = v.i + 0x7fffu + ((v.i >> 16) & 1u);   // RNE
    return (unsigned short)(r >> 16);
}
__device__ __forceinline__ float gelu_exact(float v) {
    return 0.5f * v * (1.0f + erff(v * 0.70710678118654752440f));
}

// --------------------------- MFMA GEMM core --------------------------------
// 128x128 tile, BK=32, 256 threads (4 waves in 2x2), 16x16x32 bf16 MFMA.
// A: [M,K] row-major bf16 (ushort), B: [N,K] row-major bf16 (NT gemm).
__device__ __forceinline__ void gemm_core(const unsigned short* __restrict__ A,
                                          const unsigned short* __restrict__ B,
                                          int K, int bm0, int bn0,
                                          unsigned short* ldsA, unsigned short* ldsB,
                                          v4f acc[4][4])
{
    const int tid  = threadIdx.x;
    const int wave = tid >> 6;
    const int lane = tid & 63;
    const int rowInChunk = lane >> 2;        // 0..15
    const int col8       = (lane & 3) * 8;   // element offset in BK
    const int ldsLane    = lane * 8;         // element offset in 1KB chunk
    const int c0 = wave * 2, c1 = wave * 2 + 1;
    const int wm = wave & 1, wn = wave >> 1;

    const size_t aR0 = (size_t)(bm0 + c0 * 16 + rowInChunk) * K + col8;
    const size_t aR1 = (size_t)(bm0 + c1 * 16 + rowInChunk) * K + col8;
    const size_t bR0 = (size_t)(bn0 + c0 * 16 + rowInChunk) * K + col8;
    const size_t bR1 = (size_t)(bn0 + c1 * 16 + rowInChunk) * K + col8;

    for (int k0 = 0; k0 < K; k0 += 32) {
        __builtin_amdgcn_global_load_lds((const AS_G void*)(A + aR0 + k0),
                                         (AS_L void*)(ldsA + c0 * 512 + ldsLane), 16, 0, 0);
        __builtin_amdgcn_global_load_lds((const AS_G void*)(A + aR1 + k0),
                                         (AS_L void*)(ldsA + c1 * 512 + ldsLane), 16, 0, 0);
        __builtin_amdgcn_global_load_lds((const AS_G void*)(B + bR0 + k0),
                                         (AS_L void*)(ldsB + c0 * 512 + ldsLane), 16, 0, 0);
        __builtin_amdgcn_global_load_lds((const AS_G void*)(B + bR1 + k0),
                                         (AS_L void*)(ldsB + c1 * 512 + ldsLane), 16, 0, 0);
        __syncthreads();

        v8bf af[4], bfr[4];
#pragma unroll
        for (int i = 0; i < 4; ++i)
            af[i] = *(const v8bf*)&ldsA[(wm * 64 + i * 16 + (lane & 15)) * 32 + (lane >> 4) * 8];
#pragma unroll
        for (int j = 0; j < 4; ++j)
            bfr[j] = *(const v8bf*)&ldsB[(wn * 64 + j * 16 + (lane & 15)) * 32 + (lane >> 4) * 8];
#pragma unroll
        for (int i = 0; i < 4; ++i)
#pragma unroll
            for (int j = 0; j < 4; ++j)
                acc[i][j] = __builtin_amdgcn_mfma_f32_16x16x32_bf16(af[i], bfr[j], acc[i][j], 0, 0, 0);
        __syncthreads();
    }
}

// --------------------------- kernels ---------------------------------------

// FP32 -> bf16 bulk convert, 4 elems/thread (n multiple of 4)
__global__ void f2b_kernel(const float* __restrict__ src,
                           unsigned short* __restrict__ dst, int n)
{
    int i = (blockIdx.x * 256 + threadIdx.x) * 4;
    if (i < n) {
        float4 v = *(const float4*)(src + i);
        dst[i + 0] = f2bf(v.x);
        dst[i + 1] = f2bf(v.y);
        dst[i + 2] = f2bf(v.z);
        dst[i + 3] = f2bf(v.w);
    }
}

// Build zero-padded bf16 topk operands from FP32 sources.
__global__ void pad_kernel(const float* __restrict__ x,
                           const float* __restrict__ W1,
                           unsigned short* __restrict__ xpad,
                           unsigned short* __restrict__ w1pad)
{
    int e = blockIdx.x * 256 + threadIdx.x;
    const int NX = 8192 * 128;
    if (e < NX) {
        int row = e >> 7, col = e & 127;
        xpad[e] = (col < 103) ? f2bf(x[(size_t)row * 1024 + col]) : (unsigned short)0;
    } else {
        int e2 = e - NX;
        if (e2 < 4096 * 128) {
            int row = e2 >> 7, col = e2 & 127;
            w1pad[e2] = (col < 103) ? f2bf(W1[(size_t)row * 1024 + col]) : (unsigned short)0;
        }
    }
}

// Per-row absmax scales from FP32: blocks 0..8191 -> x; 8192..12287 -> W1; 12288 -> b1
__global__ void scales_kernel(const float* __restrict__ x,
                              const float* __restrict__ W1,
                              const float* __restrict__ b1,
                              float* __restrict__ s_x, float* __restrict__ s_w,
                              float* __restrict__ s_b)
{
    int b = blockIdx.x, tid = threadIdx.x;
    const float* src; int len; float* dst;
    if (b < 8192)       { src = x  + (size_t)b * 1024;          len = 1024; dst = s_x + b; }
    else if (b < 12288) { src = W1 + (size_t)(b - 8192) * 1024; len = 1024; dst = s_w + (b - 8192); }
    else                { src = b1;                              len = 4096; dst = s_b; }
    float m = 0.f;
    for (int k = tid; k < len; k += 256) m = fmaxf(m, fabsf(src[k]));
#pragma unroll
    for (int off = 32; off; off >>= 1) m = fmaxf(m, __shfl_xor(m, off, 64));
    __shared__ float red[4];
    if ((tid & 63) == 0) red[tid >> 6] = m;
    __syncthreads();
    if (tid == 0) {
        m = fmaxf(fmaxf(red[0], red[1]), fmaxf(red[2], red[3]));
        *dst = fmaxf(m, 1e-5f) * (1.0f / 127.0f);
    }
}

// counts[n] += positives of (xpad . w1pad^T + b1) over this block's 128 rows
__global__ void topk_gemm(const unsigned short* __restrict__ xpad,
                          const unsigned short* __restrict__ w1pad,
                          const float* __restrict__ b1,
                          int* __restrict__ counts)
{
    __shared__ unsigned short ldsA[128 * 32];
    __shared__ unsigned short ldsB[128 * 32];
    v4f acc[4][4];
    v4f z = {0.f, 0.f, 0.f, 0.f};
#pragma unroll
    for (int i = 0; i < 4; ++i)
#pragma unroll
        for (int j = 0; j < 4; ++j) acc[i][j] = z;

    const int bm0 = blockIdx.x * 128, bn0 = blockIdx.y * 128;
    gemm_core(xpad, w1pad, 128, bm0, bn0, ldsA, ldsB, acc);

    const int lane = threadIdx.x & 63, wave = threadIdx.x >> 6;
    const int wn = wave >> 1;
#pragma unroll
    for (int j = 0; j < 4; ++j) {
        int n = bn0 + wn * 64 + j * 16 + (lane & 15);
        float bv = b1[n];
        int cnt = 0;
#pragma unroll
        for (int i = 0; i < 4; ++i)
#pragma unroll
            for (int r = 0; r < 4; ++r)
                cnt += (acc[i][j][r] + bv > 0.0f) ? 1 : 0;
        cnt += __shfl_xor(cnt, 16, 64);
        cnt += __shfl_xor(cnt, 32, 64);
        if (lane < 16 && cnt) atomicAdd(&counts[n], cnt);
    }
}

// h = gelu(x . W1^T + b1), bf16 out
__global__ void gemm1_gelu(const unsigned short* __restrict__ xb,
                           const unsigned short* __restrict__ w1b,
                           const float* __restrict__ b1,
                           unsigned short* __restrict__ hbuf)
{
    __shared__ unsigned short ldsA[128 * 32];
    __shared__ unsigned short ldsB[128 * 32];
    v4f acc[4][4];
    v4f z = {0.f, 0.f, 0.f, 0.f};
#pragma unroll
    for (int i = 0; i < 4; ++i)
#pragma unroll
        for (int j = 0; j < 4; ++j) acc[i][j] = z;

    const int bm0 = blockIdx.x * 128, bn0 = blockIdx.y * 128;
    gemm_core(xb, w1b, 1024, bm0, bn0, ldsA, ldsB, acc);

    const int lane = threadIdx.x & 63, wave = threadIdx.x >> 6;
    const int wm = wave & 1, wn = wave >> 1;
#pragma unroll
    for (int j = 0; j < 4; ++j) {
        int n = bn0 + wn * 64 + j * 16 + (lane & 15);
        float bv = b1[n];
#pragma unroll
        for (int i = 0; i < 4; ++i)
#pragma unroll
            for (int r = 0; r < 4; ++r) {
                int m = bm0 + wm * 64 + i * 16 + (lane >> 4) * 4 + r;
                hbuf[(size_t)m * 4096 + n] = f2bf(gelu_exact(acc[i][j][r] + bv));
            }
    }
}

// Quant-channel fixup from FP32 originals (exact reference semantics).
__global__ void fixup_kernel(const float* __restrict__ x,
                             const float* __restrict__ W1,
                             const float* __restrict__ b1,
                             const int* __restrict__ counts,
                             const float* __restrict__ s_x,
                             const float* __restrict__ s_w,
                             const float* __restrict__ s_b,
                             unsigned short* __restrict__ hbuf)
{
    const int n = blockIdx.x;
    if (counts[n] > 2048) return;   // fp channel: keep gemm1 result
    __shared__ float qw[1024];
    const float swn = s_w[n];
    for (int k = threadIdx.x; k < 1024; k += 256) {
        float q = nearbyintf(W1[(size_t)n * 1024 + k] / swn);
        qw[k] = fminf(fmaxf(q, -128.f), 127.f) * swn;
    }
    __syncthreads();
    const float sb = *s_b;
    const float bq = fminf(fmaxf(nearbyintf(b1[n] / sb), -128.f), 127.f) * sb;
    for (int m = threadIdx.x; m < 8192; m += 256) {
        const float sxm = s_x[m];
        float a = 0.f;
        for (int k = 0; k < 1024; ++k) {
            float q = nearbyintf(x[(size_t)m * 1024 + k] / sxm);
            a += fminf(fmaxf(q, -128.f), 127.f) * sxm * qw[k];
        }
        hbuf[(size_t)m * 4096 + n] = f2bf(gelu_exact(a + bq));
    }
}

// out = h . W2^T + b2, FP32 out
__global__ void gemm2_bias(const unsigned short* __restrict__ hbuf,
                           const unsigned short* __restrict__ w2b,
                           const float* __restrict__ b2,
                           float* __restrict__ out)
{
    __shared__ unsigned short ldsA[128 * 32];
    __shared__ unsigned short ldsB[128 * 32];
    v4f acc[4][4];
    v4f z = {0.f, 0.f, 0.f, 0.f};
#pragma unroll
    for (int i = 0; i < 4; ++i)
#pragma unroll
        for (int j = 0; j < 4; ++j) acc[i][j] = z;

    const int bm0 = blockIdx.x * 128, bn0 = blockIdx.y * 128;
    gemm_core(hbuf, w2b, 4096, bm0, bn0, ldsA, ldsB, acc);

    const int lane = threadIdx.x & 63, wave = threadIdx.x >> 6;
    const int wm = wave & 1, wn = wave >> 1;
#pragma unroll
    for (int j = 0; j < 4; ++j) {
        int n = bn0 + wn * 64 + j * 16 + (lane & 15);
        float bv = b2[n];
#pragma unroll
        for (int i = 0; i < 4; ++i)
#pragma unroll
            for (int r = 0; r < 4; ++r) {
                int m = bm0 + wm * 64 + i * 16 + (lane >> 4) * 4 + r;
                out[(size_t)m * 1024 + n] = acc[i][j][r] + bv;
            }
    }
}

// --------------------------- launch ----------------------------------------
extern "C" void kernel_launch(void* const* d_in, const int* in_sizes, int n_in,
                              void* d_out, int out_size, void* d_ws, size_t ws_size,
                              hipStream_t stream)
{
    const float* x  = (const float*)d_in[0];   // [4,2048,1024] fp32
    const float* W1 = (const float*)d_in[1];   // [4096,1024]
    const float* b1 = (const float*)d_in[2];   // [4096]
    const float* W2 = (const float*)d_in[3];   // [1024,4096]
    const float* b2 = (const float*)d_in[4];   // [1024]
    float* out = (float*)d_out;                // [4,2048,1024] fp32 (32 MB)

    // bf16 copies of x and W1 parked in d_out (dead until gemm2 writes it):
    unsigned short* xb  = (unsigned short*)d_out;                    // 16 MB
    unsigned short* w1b = (unsigned short*)d_out + (size_t)8192*1024; // 8 MB

    char* ws = (char*)d_ws;
    int*   counts = (int*)(ws + 0);                       // 16 KB
    float* s_x    = (float*)(ws + (64 << 10));            // 32 KB
    float* s_w    = (float*)(ws + (96 << 10));            // 16 KB
    float* s_b    = (float*)(ws + (112 << 10));           // 4 B
    unsigned short* xpad  = (unsigned short*)(ws + (1 << 20));   // 2 MB
    unsigned short* w1pad = (unsigned short*)(ws + (3 << 20));   // 1 MB
    unsigned short* w2b   = (unsigned short*)(ws + (4 << 20));   // 8 MB
    unsigned short* hbuf  = (unsigned short*)(ws + (12 << 20));  // 64 MB -> 76 MB total

    hipMemsetAsync(counts, 0, 4096 * sizeof(int), stream);

    f2b_kernel<<<8192, 256, 0, stream>>>(x,  xb,  8192 * 1024);
    f2b_kernel<<<4096, 256, 0, stream>>>(W1, w1b, 4096 * 1024);
    f2b_kernel<<<4096, 256, 0, stream>>>(W2, w2b, 1024 * 4096);
    pad_kernel<<<(8192 * 128 + 4096 * 128 + 255) / 256, 256, 0, stream>>>(x, W1, xpad, w1pad);
    scales_kernel<<<12289, 256, 0, stream>>>(x, W1, b1, s_x, s_w, s_b);
    topk_gemm<<<dim3(64, 32), 256, 0, stream>>>(xpad, w1pad, b1, counts);
    gemm1_gelu<<<dim3(64, 32), 256, 0, stream>>>(xb, w1b, b1, hbuf);
    fixup_kernel<<<4096, 256, 0, stream>>>(x, W1, b1, counts, s_x, s_w, s_b, hbuf);
    gemm2_bias<<<dim3(64, 8), 256, 0, stream>>>(hbuf, w2b, b2, out);
}

// Round 3
// 309.054 us; speedup vs baseline: 1.0897x; 1.0897x over previous
//
#include <hip/hip_runtime.h>
#include <math.h>
#include <stdint.h>

// ---------------------------------------------------------------------------
// Mlp_8744553415182 on MI355X (gfx950). FP32 I/O; bf16 MFMA compute.
//   1. prep_kernel:  x->xb(+xpad,s_x), W1->w1b(+w1pad,s_w), W2->w2b, b1->s_b,
//                    counts=0.  One fused pass, fp32 read once.
//   2. topk_gemm:    counts[n] += #(x_topk . w1_topk + b1 > 0)   (MFMA K=128)
//   3. gemm1_gelu:   h = gelu(x . W1^T + b1) bf16, ALL channels  (MFMA K=1024)
//   4. fixup_kernel: channels with counts<=2048 -> exact quantized path
//                    (statistically zero fire -> near-free, but exact if they do)
//   5. gemm2_bias:   out = h . W2^T + b2, FP32 out               (MFMA K=4096)
// LDS layout XOR-swizzled for conflict-free ds_read_b128 (R2: 8.4M conflicts).
// gelu via tanh-form exp (R2: erff epilogue was ~30% VALU tail).
// ---------------------------------------------------------------------------

typedef __bf16 v8bf __attribute__((ext_vector_type(8)));
typedef float v4f __attribute__((ext_vector_type(4)));

#define AS_G __attribute__((address_space(1)))
#define AS_L __attribute__((address_space(3)))

__device__ __forceinline__ unsigned short f2bf(float f) {
    union { float f; unsigned int i; } v; v.f = f;
    unsigned int r = v.i + 0x7fffu + ((v.i >> 16) & 1u);   // RNE
    return (unsigned short)(r >> 16);
}
// tanh-form gelu: err is even in x and ~5e-4 rms; W2 is zero-mean so the
// out-level impact is ~6e-4 rms — far under the 5.7e-2 threshold.
__device__ __forceinline__ float gelu_fast(float v) {
    float u = v * (0.79788456080286536f + 0.035677408136300125f * v * v);
    u = fminf(fmaxf(u, -15.f), 15.f);
    float e = __expf(2.0f * u);
    return v * e * __builtin_amdgcn_rcpf(e + 1.0f);   // v * e/(e+1) = 0.5v(1+tanh u)
}
__device__ __forceinline__ float gelu_exact(float v) {
    return 0.5f * v * (1.0f + erff(v * 0.70710678118654752440f));
}

// --------------------------- MFMA GEMM core --------------------------------
// 128x128 tile, BK=32, 256 threads (4 waves 2x2), 16x16x32 bf16 MFMA.
// A [M,K], B [N,K] row-major bf16.  Stage via global_load_lds width=16.
// XOR swizzle: LDS 16B-chunk l of each 1KB block holds global
// (row = l>>2, colblk = (l&3) ^ ((l>>3)&3));  reader chunk = R*4 + (Q^((R>>1)&3))
// -> every aligned lane-octet hits 8 distinct bank-quads (conflict-free).
__device__ __forceinline__ void gemm_core(const unsigned short* __restrict__ A,
                                          const unsigned short* __restrict__ B,
                                          int K, int bm0, int bn0,
                                          unsigned short* ldsA, unsigned short* ldsB,
                                          v4f acc[4][4])
{
    const int tid  = threadIdx.x;
    const int wave = tid >> 6;
    const int lane = tid & 63;
    const int rowInChunk = lane >> 2;                         // 0..15
    const int col8 = ((lane & 3) ^ ((lane >> 3) & 3)) * 8;    // swizzled K-block
    const int ldsLane = lane * 8;                             // dest: lane*16B (fixed)
    const int c0 = wave * 2, c1 = wave * 2 + 1;
    const int wm = wave & 1, wn = wave >> 1;

    const size_t aR0 = (size_t)(bm0 + c0 * 16 + rowInChunk) * K + col8;
    const size_t aR1 = (size_t)(bm0 + c1 * 16 + rowInChunk) * K + col8;
    const size_t bR0 = (size_t)(bn0 + c0 * 16 + rowInChunk) * K + col8;
    const size_t bR1 = (size_t)(bn0 + c1 * 16 + rowInChunk) * K + col8;

    const int R = lane & 15, Q = lane >> 4;
    const int roff = R * 32 + ((Q ^ ((R >> 1) & 3)) * 8);     // swizzled read offset

    for (int k0 = 0; k0 < K; k0 += 32) {
        __builtin_amdgcn_global_load_lds((const AS_G void*)(A + aR0 + k0),
                                         (AS_L void*)(ldsA + c0 * 512 + ldsLane), 16, 0, 0);
        __builtin_amdgcn_global_load_lds((const AS_G void*)(A + aR1 + k0),
                                         (AS_L void*)(ldsA + c1 * 512 + ldsLane), 16, 0, 0);
        __builtin_amdgcn_global_load_lds((const AS_G void*)(B + bR0 + k0),
                                         (AS_L void*)(ldsB + c0 * 512 + ldsLane), 16, 0, 0);
        __builtin_amdgcn_global_load_lds((const AS_G void*)(B + bR1 + k0),
                                         (AS_L void*)(ldsB + c1 * 512 + ldsLane), 16, 0, 0);
        __syncthreads();

        v8bf af[4], bfr[4];
#pragma unroll
        for (int i = 0; i < 4; ++i)
            af[i] = *(const v8bf*)&ldsA[(wm * 4 + i) * 512 + roff];
#pragma unroll
        for (int j = 0; j < 4; ++j)
            bfr[j] = *(const v8bf*)&ldsB[(wn * 4 + j) * 512 + roff];
#pragma unroll
        for (int i = 0; i < 4; ++i)
#pragma unroll
            for (int j = 0; j < 4; ++j)
                acc[i][j] = __builtin_amdgcn_mfma_f32_16x16x32_bf16(af[i], bfr[j], acc[i][j], 0, 0, 0);
        __syncthreads();
    }
}

// --------------------------- prep (fused) -----------------------------------
// blocks 0..8191: x row -> xb row + xpad row + s_x
// blocks 8192..12287: W1 row -> w1b row + w1pad row + s_w
// blocks 12288..16383: W2 1K-chunk -> w2b
// block 16384: b1 -> s_b; counts = 0
__global__ void prep_kernel(const float* __restrict__ x, const float* __restrict__ W1,
                            const float* __restrict__ W2, const float* __restrict__ b1,
                            unsigned short* __restrict__ xb, unsigned short* __restrict__ w1b,
                            unsigned short* __restrict__ w2b,
                            unsigned short* __restrict__ xpad, unsigned short* __restrict__ w1pad,
                            float* __restrict__ s_x, float* __restrict__ s_w,
                            float* __restrict__ s_b, int* __restrict__ counts)
{
    const int b = blockIdx.x, t = threadIdx.x;
    __shared__ float red[4];

    if (b < 16384) {
        const float* src; unsigned short* dst; unsigned short* pad = nullptr; float* sc = nullptr;
        if (b < 8192)       { src = x  + (size_t)b * 1024;            dst = xb  + (size_t)b * 1024;
                              pad = xpad  + (size_t)b * 128;          sc = s_x + b; }
        else if (b < 12288) { int r = b - 8192;  src = W1 + (size_t)r * 1024; dst = w1b + (size_t)r * 1024;
                              pad = w1pad + (size_t)r * 128;          sc = s_w + r; }
        else                { int r = b - 12288; src = W2 + (size_t)r * 1024; dst = w2b + (size_t)r * 1024; }

        float4 v = ((const float4*)src)[t];
        ushort4 u;
        u.x = f2bf(v.x); u.y = f2bf(v.y); u.z = f2bf(v.z); u.w = f2bf(v.w);
        ((ushort4*)dst)[t] = u;
        if (pad && t < 32) {
            int c = t * 4;
            ushort4 p;
            p.x = (c + 0 < 103) ? u.x : (unsigned short)0;
            p.y = (c + 1 < 103) ? u.y : (unsigned short)0;
            p.z = (c + 2 < 103) ? u.z : (unsigned short)0;
            p.w = (c + 3 < 103) ? u.w : (unsigned short)0;
            ((ushort4*)pad)[t] = p;
        }
        if (sc) {
            float m = fmaxf(fmaxf(fabsf(v.x), fabsf(v.y)), fmaxf(fabsf(v.z), fabsf(v.w)));
#pragma unroll
            for (int off = 32; off; off >>= 1) m = fmaxf(m, __shfl_xor(m, off, 64));
            if ((t & 63) == 0) red[t >> 6] = m;
            __syncthreads();
            if (t == 0) {
                m = fmaxf(fmaxf(red[0], red[1]), fmaxf(red[2], red[3]));
                *sc = fmaxf(m, 1e-5f) * (1.0f / 127.0f);
            }
        }
    } else {
        float m = 0.f;
        for (int k = t; k < 4096; k += 256) { m = fmaxf(m, fabsf(b1[k])); counts[k] = 0; }
#pragma unroll
        for (int off = 32; off; off >>= 1) m = fmaxf(m, __shfl_xor(m, off, 64));
        if ((t & 63) == 0) red[t >> 6] = m;
        __syncthreads();
        if (t == 0) {
            m = fmaxf(fmaxf(red[0], red[1]), fmaxf(red[2], red[3]));
            *s_b = fmaxf(m, 1e-5f) * (1.0f / 127.0f);
        }
    }
}

// --------------------------- topk counts ------------------------------------
__global__ void topk_gemm(const unsigned short* __restrict__ xpad,
                          const unsigned short* __restrict__ w1pad,
                          const float* __restrict__ b1,
                          int* __restrict__ counts)
{
    __shared__ unsigned short ldsA[128 * 32];
    __shared__ unsigned short ldsB[128 * 32];
    v4f acc[4][4];
    v4f z = {0.f, 0.f, 0.f, 0.f};
#pragma unroll
    for (int i = 0; i < 4; ++i)
#pragma unroll
        for (int j = 0; j < 4; ++j) acc[i][j] = z;

    const int bm0 = blockIdx.x * 128, bn0 = blockIdx.y * 128;
    gemm_core(xpad, w1pad, 128, bm0, bn0, ldsA, ldsB, acc);

    const int lane = threadIdx.x & 63, wave = threadIdx.x >> 6;
    const int wn = wave >> 1;
#pragma unroll
    for (int j = 0; j < 4; ++j) {
        int n = bn0 + wn * 64 + j * 16 + (lane & 15);
        float bv = b1[n];
        int cnt = 0;
#pragma unroll
        for (int i = 0; i < 4; ++i)
#pragma unroll
            for (int r = 0; r < 4; ++r)
                cnt += (acc[i][j][r] + bv > 0.0f) ? 1 : 0;
        cnt += __shfl_xor(cnt, 16, 64);
        cnt += __shfl_xor(cnt, 32, 64);
        if (lane < 16 && cnt) atomicAdd(&counts[n], cnt);
    }
}

// --------------------------- gemm1 + gelu ------------------------------------
__global__ void gemm1_gelu(const unsigned short* __restrict__ xb,
                           const unsigned short* __restrict__ w1b,
                           const float* __restrict__ b1,
                           unsigned short* __restrict__ hbuf)
{
    __shared__ unsigned short ldsA[128 * 32];
    __shared__ unsigned short ldsB[128 * 32];
    v4f acc[4][4];
    v4f z = {0.f, 0.f, 0.f, 0.f};
#pragma unroll
    for (int i = 0; i < 4; ++i)
#pragma unroll
        for (int j = 0; j < 4; ++j) acc[i][j] = z;

    const int bm0 = blockIdx.x * 128, bn0 = blockIdx.y * 128;
    gemm_core(xb, w1b, 1024, bm0, bn0, ldsA, ldsB, acc);

    const int lane = threadIdx.x & 63, wave = threadIdx.x >> 6;
    const int wm = wave & 1, wn = wave >> 1;
#pragma unroll
    for (int j = 0; j < 4; ++j) {
        int n = bn0 + wn * 64 + j * 16 + (lane & 15);
        float bv = b1[n];
#pragma unroll
        for (int i = 0; i < 4; ++i)
#pragma unroll
            for (int r = 0; r < 4; ++r) {
                int m = bm0 + wm * 64 + i * 16 + (lane >> 4) * 4 + r;
                hbuf[(size_t)m * 4096 + n] = f2bf(gelu_fast(acc[i][j][r] + bv));
            }
    }
}

// --------------------------- fixup (exact quant path) ------------------------
__global__ void fixup_kernel(const float* __restrict__ x,
                             const float* __restrict__ W1,
                             const float* __restrict__ b1,
                             const int* __restrict__ counts,
                             const float* __restrict__ s_x,
                             const float* __restrict__ s_w,
                             const float* __restrict__ s_b,
                             unsigned short* __restrict__ hbuf)
{
    const int n = blockIdx.x;
    if (counts[n] > 2048) return;   // fp channel: keep gemm1 result
    __shared__ float qw[1024];
    const float swn = s_w[n];
    for (int k = threadIdx.x; k < 1024; k += 256) {
        float q = nearbyintf(W1[(size_t)n * 1024 + k] / swn);
        qw[k] = fminf(fmaxf(q, -128.f), 127.f) * swn;
    }
    __syncthreads();
    const float sb = *s_b;
    const float bq = fminf(fmaxf(nearbyintf(b1[n] / sb), -128.f), 127.f) * sb;
    for (int m = threadIdx.x; m < 8192; m += 256) {
        const float sxm = s_x[m];
        float a = 0.f;
        for (int k = 0; k < 1024; ++k) {
            float q = nearbyintf(x[(size_t)m * 1024 + k] / sxm);
            a += fminf(fmaxf(q, -128.f), 127.f) * sxm * qw[k];
        }
        hbuf[(size_t)m * 4096 + n] = f2bf(gelu_exact(a + bq));
    }
}

// --------------------------- gemm2 + bias ------------------------------------
__global__ void gemm2_bias(const unsigned short* __restrict__ hbuf,
                           const unsigned short* __restrict__ w2b,
                           const float* __restrict__ b2,
                           float* __restrict__ out)
{
    __shared__ unsigned short ldsA[128 * 32];
    __shared__ unsigned short ldsB[128 * 32];
    v4f acc[4][4];
    v4f z = {0.f, 0.f, 0.f, 0.f};
#pragma unroll
    for (int i = 0; i < 4; ++i)
#pragma unroll
        for (int j = 0; j < 4; ++j) acc[i][j] = z;

    const int bm0 = blockIdx.x * 128, bn0 = blockIdx.y * 128;
    gemm_core(hbuf, w2b, 4096, bm0, bn0, ldsA, ldsB, acc);

    const int lane = threadIdx.x & 63, wave = threadIdx.x >> 6;
    const int wm = wave & 1, wn = wave >> 1;
#pragma unroll
    for (int j = 0; j < 4; ++j) {
        int n = bn0 + wn * 64 + j * 16 + (lane & 15);
        float bv = b2[n];
#pragma unroll
        for (int i = 0; i < 4; ++i)
#pragma unroll
            for (int r = 0; r < 4; ++r) {
                int m = bm0 + wm * 64 + i * 16 + (lane >> 4) * 4 + r;
                out[(size_t)m * 1024 + n] = acc[i][j][r] + bv;
            }
    }
}

// --------------------------- launch ----------------------------------------
extern "C" void kernel_launch(void* const* d_in, const int* in_sizes, int n_in,
                              void* d_out, int out_size, void* d_ws, size_t ws_size,
                              hipStream_t stream)
{
    const float* x  = (const float*)d_in[0];   // [4,2048,1024] fp32
    const float* W1 = (const float*)d_in[1];   // [4096,1024]
    const float* b1 = (const float*)d_in[2];   // [4096]
    const float* W2 = (const float*)d_in[3];   // [1024,4096]
    const float* b2 = (const float*)d_in[4];   // [1024]
    float* out = (float*)d_out;                // [4,2048,1024] fp32 (32 MB)

    // bf16 copies of x and W1 parked in d_out (dead until gemm2 writes it):
    unsigned short* xb  = (unsigned short*)d_out;                      // 16 MB
    unsigned short* w1b = (unsigned short*)d_out + (size_t)8192 * 1024; // 8 MB

    char* ws = (char*)d_ws;
    int*   counts = (int*)(ws + 0);                       // 16 KB
    float* s_x    = (float*)(ws + (64 << 10));            // 32 KB
    float* s_w    = (float*)(ws + (96 << 10));            // 16 KB
    float* s_b    = (float*)(ws + (112 << 10));           // 4 B
    unsigned short* xpad  = (unsigned short*)(ws + (1 << 20));   // 2 MB
    unsigned short* w1pad = (unsigned short*)(ws + (3 << 20));   // 1 MB
    unsigned short* w2b   = (unsigned short*)(ws + (4 << 20));   // 8 MB
    unsigned short* hbuf  = (unsigned short*)(ws + (12 << 20));  // 64 MB -> 76 MB total

    prep_kernel<<<16385, 256, 0, stream>>>(x, W1, W2, b1, xb, w1b, w2b,
                                           xpad, w1pad, s_x, s_w, s_b, counts);
    topk_gemm<<<dim3(64, 32), 256, 0, stream>>>(xpad, w1pad, b1, counts);
    gemm1_gelu<<<dim3(64, 32), 256, 0, stream>>>(xb, w1b, b1, hbuf);
    fixup_kernel<<<4096, 256, 0, stream>>>(x, W1, b1, counts, s_x, s_w, s_b, hbuf);
    gemm2_bias<<<dim3(64, 8), 256, 0, stream>>>(hbuf, w2b, b2, out);
}